// Round 4
// baseline (423.381 us; speedup 1.0000x reference)
//
#include <hip/hip_runtime.h>

// ---------------------------------------------------------------------------
// AWQ int4 dequant GEMM: out = x @ dequant(qweight, scales, qzeros) + bias
// M=4096, K=4096, N=11008, group=128
//   1) convert_x: fp32->bf16 A[M][K]
//   2) dequant_awq: int4 -> bf16 Bt[N][K]
//   3) gemm_bf16: 256x256 8-phase, BK=64, 512 thr, counted vmcnt(6),
//      XOR-swizzled LDS, ONE-PHASE-AHEAD ds_read prefetch with counted
//      lgkmcnt (reads overlap MFMA), bias fused.
// ---------------------------------------------------------------------------

typedef __bf16 bf16x8 __attribute__((ext_vector_type(8)));
typedef float f32x4 __attribute__((ext_vector_type(4)));
typedef unsigned short ushort8 __attribute__((ext_vector_type(8)));

__device__ __forceinline__ unsigned short f2bf(float f) {
  unsigned int u = __builtin_bit_cast(unsigned int, f);
  u += 0x7FFFu + ((u >> 16) & 1u);
  return (unsigned short)(u >> 16);
}

__device__ __forceinline__ void gload16(const void* g, void* l) {
  __builtin_amdgcn_global_load_lds(
      (const __attribute__((address_space(1))) unsigned int*)g,
      (__attribute__((address_space(3))) unsigned int*)l, 16, 0, 0);
}

// ---------------------------------------------------------------------------
// Kernel 1: x fp32 -> A bf16
// ---------------------------------------------------------------------------
__global__ __launch_bounds__(256) void convert_x(const float* __restrict__ x,
                                                 unsigned short* __restrict__ A,
                                                 long long n8) {
  for (long long idx = (long long)blockIdx.x * 256 + threadIdx.x; idx < n8;
       idx += (long long)gridDim.x * 256) {
    float4 u = ((const float4*)x)[2 * idx];
    float4 v = ((const float4*)x)[2 * idx + 1];
    ushort8 o;
    o[0] = f2bf(u.x); o[1] = f2bf(u.y); o[2] = f2bf(u.z); o[3] = f2bf(u.w);
    o[4] = f2bf(v.x); o[5] = f2bf(v.y); o[6] = f2bf(v.z); o[7] = f2bf(v.w);
    ((ushort8*)A)[idx] = o;
  }
}

// ---------------------------------------------------------------------------
// Kernel 2: AWQ dequant + transpose -> Bt bf16 [N][K]
// ---------------------------------------------------------------------------
__global__ __launch_bounds__(256) void dequant_awq(const int* __restrict__ qw,
                                                   const float* __restrict__ sc,
                                                   const int* __restrict__ qz,
                                                   unsigned short* __restrict__ Bt,
                                                   int K, int N) {
  const int n8w = N >> 3;
  const int tiles_n = N >> 6;
  const int tk = blockIdx.x / tiles_n;
  const int tn = blockIdx.x % tiles_n;
  const int k0 = tk << 6, n0 = tn << 6;
  const int g = k0 >> 7;
  __shared__ unsigned short tile[64][72];
  __shared__ float s_s[64];
  __shared__ float s_z[64];
  const int t = threadIdx.x;
  if (t < 64) {
    s_s[t] = sc[(size_t)g * N + n0 + t];
  } else if (t < 72) {
    const int j = t - 64;
    const int zq = qz[(size_t)g * n8w + (n0 >> 3) + j];
    s_z[j * 8 + 0] = (float)((zq >> 0) & 0xF);
    s_z[j * 8 + 1] = (float)((zq >> 16) & 0xF);
    s_z[j * 8 + 2] = (float)((zq >> 4) & 0xF);
    s_z[j * 8 + 3] = (float)((zq >> 20) & 0xF);
    s_z[j * 8 + 4] = (float)((zq >> 8) & 0xF);
    s_z[j * 8 + 5] = (float)((zq >> 24) & 0xF);
    s_z[j * 8 + 6] = (float)((zq >> 12) & 0xF);
    s_z[j * 8 + 7] = (float)((zq >> 28) & 0xF);
  }
  __syncthreads();
#pragma unroll
  for (int r = 0; r < 2; ++r) {
    const int d = (r << 8) + t;
    const int kk = d >> 3, j = d & 7;
    const int q = qw[(size_t)(k0 + kk) * n8w + (n0 >> 3) + j];
    const int base = j << 3;
    ushort8 o;
    o[0] = f2bf(((float)((q >> 0) & 0xF) - s_z[base + 0]) * s_s[base + 0]);
    o[1] = f2bf(((float)((q >> 16) & 0xF) - s_z[base + 1]) * s_s[base + 1]);
    o[2] = f2bf(((float)((q >> 4) & 0xF) - s_z[base + 2]) * s_s[base + 2]);
    o[3] = f2bf(((float)((q >> 20) & 0xF) - s_z[base + 3]) * s_s[base + 3]);
    o[4] = f2bf(((float)((q >> 8) & 0xF) - s_z[base + 4]) * s_s[base + 4]);
    o[5] = f2bf(((float)((q >> 24) & 0xF) - s_z[base + 5]) * s_s[base + 5]);
    o[6] = f2bf(((float)((q >> 12) & 0xF) - s_z[base + 6]) * s_s[base + 6]);
    o[7] = f2bf(((float)((q >> 28) & 0xF) - s_z[base + 7]) * s_s[base + 7]);
    *(ushort8*)&tile[kk][base] = o;
  }
  __syncthreads();
#pragma unroll
  for (int r = 0; r < 2; ++r) {
    const int d = (r << 8) + t;
    const int nl = d >> 3, seg = d & 7;
    ushort8 o;
#pragma unroll
    for (int i = 0; i < 8; ++i) o[i] = tile[(seg << 3) + i][nl];
    *(ushort8*)&Bt[(size_t)(n0 + nl) * K + k0 + (seg << 3)] = o;
  }
}

// ---------------------------------------------------------------------------
// Kernel 3: 256x256 8-phase bf16 GEMM with one-phase-ahead fragment prefetch.
// A [M][K], Bt [N][K], C fp32 [M][N]. 8 waves (2M x 4N), per-wave 128x64.
// LDS: 2 bufs x (A[256][64] + B[256][64]) = 128 KiB, XOR-swizzled content.
// Phase p issues ds_reads for phase p+1's fragments, waits lgkmcnt(R_next)
// so those reads execute under phase p's MFMA cluster.
// Read-issue schedule per tile: ph1->a1(8), ph2->bb1(4), ph3->none,
// ph4->next tile's a0,bb0 (12; safe: after vmcnt(6)+barrier, tile t+1 is
// fully published; region overwrite schedule verified dead-before-write).
// ---------------------------------------------------------------------------
#define BM 256
#define BN 256
#define BK 64

__global__ __launch_bounds__(512, 2) void gemm_bf16(const unsigned short* __restrict__ A,
                                                    const unsigned short* __restrict__ Bt,
                                                    const float* __restrict__ bias,
                                                    float* __restrict__ C,
                                                    int M, int N, int K) {
  __shared__ __align__(16) unsigned short sm[2][32768];
  const int tid = threadIdx.x;
  const int w = tid >> 6, lane = tid & 63;
  const int wm = w >> 2, wn = w & 3;

  // T1: XCD-aware swizzle (grid = 688, 688 % 8 == 0 -> exact)
  const int nbn = N / BN;
  const int cpx = gridDim.x >> 3;
  const int g = (blockIdx.x & 7) * cpx + (blockIdx.x >> 3);
  const int bm = g / nbn, bn = g % nbn;
  const int brow = bm * BM, bcol = bn * BN;

  // staging: thread covers row srow(+i*64+(h&1)*128), pre-swizzled k chunk
  const int srow = tid >> 3;                                // 0..63
  const int kswz = ((tid & 7) ^ (srow & 7)) << 3;           // shorts
  const unsigned short* pA = A + (size_t)(brow + srow) * K + kswz;
  const unsigned short* pB = Bt + (size_t)(bcol + srow) * K + kswz;

  // frag reads: row R = base + (lane&15); col bytes = (ks*64+q*16) ^ ((R&7)<<4)
  const int aBase = (wm * 128 + (lane & 15)) * 64;          // shorts
  const int bBase = 16384 + (wn * 64 + (lane & 15)) * 64;
  const int col0 = (((lane >> 4) * 16) ^ ((lane & 7) << 4)) >> 1;        // shorts
  const int col1 = ((64 + (lane >> 4) * 16) ^ ((lane & 7) << 4)) >> 1;

  const int NKt = K / BK;
  const int nhalf = NKt * 4;

  f32x4 acc[8][4];
#pragma unroll
  for (int m = 0; m < 8; ++m)
#pragma unroll
    for (int n = 0; n < 4; ++n) acc[m][n] = (f32x4){0.f, 0.f, 0.f, 0.f};

  auto stage_half = [&](int s) {
    if (s < nhalf) {
      const int kt = s >> 2, h = s & 3;
      const unsigned short* src =
          ((h & 2) ? pB : pA) + (size_t)((h & 1) * 128) * K + (size_t)kt * BK;
      unsigned short* dst = &sm[kt & 1][(h << 13) + (w << 9)];
      gload16(src, dst);
      gload16(src + (size_t)64 * K, dst + 4096);
    }
  };

  bf16x8 a0[4][2], a1[4][2], bb0[2][2], bb1[2][2];

  auto read_a0b0 = [&](const unsigned short* bp) {  // 12 ds_read_b128
#pragma unroll
    for (int m = 0; m < 4; ++m) {
      a0[m][0] = *(const bf16x8*)(bp + aBase + m * 1024 + col0);
      a0[m][1] = *(const bf16x8*)(bp + aBase + m * 1024 + col1);
    }
#pragma unroll
    for (int n = 0; n < 2; ++n) {
      bb0[n][0] = *(const bf16x8*)(bp + bBase + n * 1024 + col0);
      bb0[n][1] = *(const bf16x8*)(bp + bBase + n * 1024 + col1);
    }
  };
  auto read_a1 = [&](const unsigned short* bp) {    // 8 ds_read_b128
#pragma unroll
    for (int m = 0; m < 4; ++m) {
      a1[m][0] = *(const bf16x8*)(bp + aBase + 4096 + m * 1024 + col0);
      a1[m][1] = *(const bf16x8*)(bp + aBase + 4096 + m * 1024 + col1);
    }
  };
  auto read_b1 = [&](const unsigned short* bp) {    // 4 ds_read_b128
#pragma unroll
    for (int n = 0; n < 2; ++n) {
      bb1[n][0] = *(const bf16x8*)(bp + bBase + (n + 2) * 1024 + col0);
      bb1[n][1] = *(const bf16x8*)(bp + bBase + (n + 2) * 1024 + col1);
    }
  };

  // prologue: tile0 (4 halves) + tile1 h0-2; drain tile0; pre-issue ph1 frags
  for (int s = 0; s < 7; ++s) stage_half(s);
  asm volatile("s_waitcnt vmcnt(6)" ::: "memory");
  __builtin_amdgcn_s_barrier();
  __builtin_amdgcn_sched_barrier(0);
  read_a0b0(sm[0]);

  for (int t = 0; t < NKt; ++t) {
    const unsigned short* bp = sm[t & 1];
    const unsigned short* bpn = sm[(t + 1) & 1];
    const int sb = 4 * t + 7;

    // ---- phase 1: MFMA q0 (a0,bb0); prefetch a1 under it ----
    stage_half(sb + 0);
    __builtin_amdgcn_s_barrier();
    __builtin_amdgcn_sched_barrier(0);
    read_a1(bp);
    asm volatile("s_waitcnt lgkmcnt(8)" ::: "memory");
    __builtin_amdgcn_sched_barrier(0);
    __builtin_amdgcn_s_setprio(1);
#pragma unroll
    for (int kk = 0; kk < 2; ++kk)
#pragma unroll
      for (int m = 0; m < 4; ++m)
#pragma unroll
        for (int n = 0; n < 2; ++n)
          acc[m][n] = __builtin_amdgcn_mfma_f32_16x16x32_bf16(a0[m][kk], bb0[n][kk], acc[m][n], 0, 0, 0);
    __builtin_amdgcn_s_setprio(0);
    __builtin_amdgcn_s_barrier();

    // ---- phase 2: MFMA q1 (a1,bb0); prefetch bb1 under it ----
    stage_half(sb + 1);
    __builtin_amdgcn_s_barrier();
    __builtin_amdgcn_sched_barrier(0);
    read_b1(bp);
    asm volatile("s_waitcnt lgkmcnt(4)" ::: "memory");
    __builtin_amdgcn_sched_barrier(0);
    __builtin_amdgcn_s_setprio(1);
#pragma unroll
    for (int kk = 0; kk < 2; ++kk)
#pragma unroll
      for (int m = 0; m < 4; ++m)
#pragma unroll
        for (int n = 0; n < 2; ++n)
          acc[4 + m][n] = __builtin_amdgcn_mfma_f32_16x16x32_bf16(a1[m][kk], bb0[n][kk], acc[4 + m][n], 0, 0, 0);
    __builtin_amdgcn_s_setprio(0);
    __builtin_amdgcn_s_barrier();

    // ---- phase 3: MFMA q2 (a0,bb1); nothing to prefetch ----
    stage_half(sb + 2);
    __builtin_amdgcn_s_barrier();
    asm volatile("s_waitcnt lgkmcnt(0)" ::: "memory");
    __builtin_amdgcn_sched_barrier(0);
    __builtin_amdgcn_s_setprio(1);
#pragma unroll
    for (int kk = 0; kk < 2; ++kk)
#pragma unroll
      for (int m = 0; m < 4; ++m)
#pragma unroll
        for (int n = 0; n < 2; ++n)
          acc[m][2 + n] = __builtin_amdgcn_mfma_f32_16x16x32_bf16(a0[m][kk], bb1[n][kk], acc[m][2 + n], 0, 0, 0);
    __builtin_amdgcn_s_setprio(0);
    __builtin_amdgcn_s_barrier();

    // ---- phase 4: MFMA q3 (a1,bb1); prefetch next tile's a0,bb0 under it ----
    stage_half(sb + 3);
    if (t < NKt - 2) {
      asm volatile("s_waitcnt vmcnt(6)" ::: "memory");
    } else {
      asm volatile("s_waitcnt vmcnt(0)" ::: "memory");
    }
    __builtin_amdgcn_s_barrier();
    __builtin_amdgcn_sched_barrier(0);
    if (t + 1 < NKt) read_a0b0(bpn);
    __builtin_amdgcn_sched_barrier(0);
    __builtin_amdgcn_s_setprio(1);
#pragma unroll
    for (int kk = 0; kk < 2; ++kk)
#pragma unroll
      for (int m = 0; m < 4; ++m)
#pragma unroll
        for (int n = 0; n < 2; ++n)
          acc[4 + m][2 + n] = __builtin_amdgcn_mfma_f32_16x16x32_bf16(a1[m][kk], bb1[n][kk], acc[4 + m][2 + n], 0, 0, 0);
    __builtin_amdgcn_s_setprio(0);
    __builtin_amdgcn_s_barrier();
  }

  // epilogue: C/D layout col=lane&15, row=(lane>>4)*4+reg
#pragma unroll
  for (int n = 0; n < 4; ++n) {
    const int col = bcol + wn * 64 + n * 16 + (lane & 15);
    const float bv = bias[col];
#pragma unroll
    for (int m = 0; m < 8; ++m) {
      const int row0 = brow + wm * 128 + m * 16 + ((lane >> 4) << 2);
#pragma unroll
      for (int q = 0; q < 4; ++q)
        C[(size_t)(row0 + q) * N + col] = acc[m][n][q] + bv;
    }
  }
}

// ---------------------------------------------------------------------------
extern "C" void kernel_launch(void* const* d_in, const int* in_sizes, int n_in,
                              void* d_out, int out_size, void* d_ws, size_t ws_size,
                              hipStream_t stream) {
  const float* x = (const float*)d_in[0];
  const int* qw = (const int*)d_in[1];
  const float* sc = (const float*)d_in[2];
  const int* qz = (const int*)d_in[3];
  const float* bias = (const float*)d_in[4];
  float* out = (float*)d_out;

  const int N = in_sizes[4];                              // 11008
  const int K = (int)(((long long)in_sizes[1] * 8) / N);  // 4096
  const int M = in_sizes[0] / K;                          // 4096

  const size_t a_elems = (size_t)M * K;
  const size_t b_elems = (size_t)N * K;
  const size_t need = (a_elems + b_elems) * sizeof(unsigned short);
  if (ws_size < need) return;

  unsigned short* A = (unsigned short*)d_ws;
  unsigned short* Bt = A + a_elems;

  convert_x<<<2048, 256, 0, stream>>>(x, A, (long long)(a_elems / 8));
  dequant_awq<<<(K / 64) * (N / 64), 256, 0, stream>>>(qw, sc, qz, Bt, K, N);
  gemm_bf16<<<(M / BM) * (N / BN), 512, 0, stream>>>(A, Bt, bias, out, M, N, K);
}

// Round 5
// 398.281 us; speedup vs baseline: 1.0630x; 1.0630x over previous
//
#include <hip/hip_runtime.h>

// ---------------------------------------------------------------------------
// AWQ int4 dequant GEMM: out = x @ dequant(qweight, scales, qzeros) + bias
// M=4096, K=4096, N=11008, group=128
//   1) convert_x: fp32->bf16 A[M][K]
//   2) dequant_awq: int4 -> bf16 Bt[N][K]
//   3) gemm_bf16: 256x256, BK=64, 512 thr, FREE-RUN tile body: 1 barrier/tile,
//      all staging + all 24 ds_reads issued up front, counted lgkmcnt(12/4/0)
//      gates 4 MFMA quadrants (AITER-style), XOR-swizzled LDS, bias fused.
// ---------------------------------------------------------------------------

typedef __bf16 bf16x8 __attribute__((ext_vector_type(8)));
typedef float f32x4 __attribute__((ext_vector_type(4)));
typedef unsigned short ushort8 __attribute__((ext_vector_type(8)));

__device__ __forceinline__ unsigned short f2bf(float f) {
  unsigned int u = __builtin_bit_cast(unsigned int, f);
  u += 0x7FFFu + ((u >> 16) & 1u);
  return (unsigned short)(u >> 16);
}

__device__ __forceinline__ void gload16(const void* g, void* l) {
  __builtin_amdgcn_global_load_lds(
      (const __attribute__((address_space(1))) unsigned int*)g,
      (__attribute__((address_space(3))) unsigned int*)l, 16, 0, 0);
}

// ---------------------------------------------------------------------------
// Kernel 1: x fp32 -> A bf16
// ---------------------------------------------------------------------------
__global__ __launch_bounds__(256) void convert_x(const float* __restrict__ x,
                                                 unsigned short* __restrict__ A,
                                                 long long n8) {
  for (long long idx = (long long)blockIdx.x * 256 + threadIdx.x; idx < n8;
       idx += (long long)gridDim.x * 256) {
    float4 u = ((const float4*)x)[2 * idx];
    float4 v = ((const float4*)x)[2 * idx + 1];
    ushort8 o;
    o[0] = f2bf(u.x); o[1] = f2bf(u.y); o[2] = f2bf(u.z); o[3] = f2bf(u.w);
    o[4] = f2bf(v.x); o[5] = f2bf(v.y); o[6] = f2bf(v.z); o[7] = f2bf(v.w);
    ((ushort8*)A)[idx] = o;
  }
}

// ---------------------------------------------------------------------------
// Kernel 2: AWQ dequant + transpose -> Bt bf16 [N][K]
// ---------------------------------------------------------------------------
__global__ __launch_bounds__(256) void dequant_awq(const int* __restrict__ qw,
                                                   const float* __restrict__ sc,
                                                   const int* __restrict__ qz,
                                                   unsigned short* __restrict__ Bt,
                                                   int K, int N) {
  const int n8w = N >> 3;
  const int tiles_n = N >> 6;
  const int tk = blockIdx.x / tiles_n;
  const int tn = blockIdx.x % tiles_n;
  const int k0 = tk << 6, n0 = tn << 6;
  const int g = k0 >> 7;
  __shared__ unsigned short tile[64][72];
  __shared__ float s_s[64];
  __shared__ float s_z[64];
  const int t = threadIdx.x;
  if (t < 64) {
    s_s[t] = sc[(size_t)g * N + n0 + t];
  } else if (t < 72) {
    const int j = t - 64;
    const int zq = qz[(size_t)g * n8w + (n0 >> 3) + j];
    s_z[j * 8 + 0] = (float)((zq >> 0) & 0xF);
    s_z[j * 8 + 1] = (float)((zq >> 16) & 0xF);
    s_z[j * 8 + 2] = (float)((zq >> 4) & 0xF);
    s_z[j * 8 + 3] = (float)((zq >> 20) & 0xF);
    s_z[j * 8 + 4] = (float)((zq >> 8) & 0xF);
    s_z[j * 8 + 5] = (float)((zq >> 24) & 0xF);
    s_z[j * 8 + 6] = (float)((zq >> 12) & 0xF);
    s_z[j * 8 + 7] = (float)((zq >> 28) & 0xF);
  }
  __syncthreads();
#pragma unroll
  for (int r = 0; r < 2; ++r) {
    const int d = (r << 8) + t;
    const int kk = d >> 3, j = d & 7;
    const int q = qw[(size_t)(k0 + kk) * n8w + (n0 >> 3) + j];
    const int base = j << 3;
    ushort8 o;
    o[0] = f2bf(((float)((q >> 0) & 0xF) - s_z[base + 0]) * s_s[base + 0]);
    o[1] = f2bf(((float)((q >> 16) & 0xF) - s_z[base + 1]) * s_s[base + 1]);
    o[2] = f2bf(((float)((q >> 4) & 0xF) - s_z[base + 2]) * s_s[base + 2]);
    o[3] = f2bf(((float)((q >> 20) & 0xF) - s_z[base + 3]) * s_s[base + 3]);
    o[4] = f2bf(((float)((q >> 8) & 0xF) - s_z[base + 4]) * s_s[base + 4]);
    o[5] = f2bf(((float)((q >> 24) & 0xF) - s_z[base + 5]) * s_s[base + 5]);
    o[6] = f2bf(((float)((q >> 12) & 0xF) - s_z[base + 6]) * s_s[base + 6]);
    o[7] = f2bf(((float)((q >> 28) & 0xF) - s_z[base + 7]) * s_s[base + 7]);
    *(ushort8*)&tile[kk][base] = o;
  }
  __syncthreads();
#pragma unroll
  for (int r = 0; r < 2; ++r) {
    const int d = (r << 8) + t;
    const int nl = d >> 3, seg = d & 7;
    ushort8 o;
#pragma unroll
    for (int i = 0; i < 8; ++i) o[i] = tile[(seg << 3) + i][nl];
    *(ushort8*)&Bt[(size_t)(n0 + nl) * K + k0 + (seg << 3)] = o;
  }
}

// ---------------------------------------------------------------------------
// Kernel 3: 256x256 free-run bf16 GEMM.  A [M][K], Bt [N][K], C fp32 [M][N].
// 8 waves (2M x 4N), per-wave 128x64 output = acc[8][4] f32x4.
// LDS: 2 bufs x (A[256][64] + B[256][64]) = 128 KiB, XOR-swizzled content.
// Per tile: ONE barrier.  Body: stage tile t+1 (8 gload16) -> issue 24
// ds_read_b128 in pinned order [a0,bb0 | a1 | bb1] -> lgkmcnt(12) MFMA q0
// -> lgkmcnt(4) MFMA q1 -> lgkmcnt(0) MFMA q2,q3 -> vmcnt(0) -> barrier.
// Hazards: staging t+1 overwrites buf[(t+1)&1], last read in tile t-1 and
// drained (lgkmcnt(0)) before each wave reached the tile-t barrier.  Reads
// of buf[t&1] were staged in t-1 and drained by its vmcnt(0)+barrier.
// ---------------------------------------------------------------------------
#define BM 256
#define BN 256
#define BK 64

__global__ __launch_bounds__(512, 2) void gemm_bf16(const unsigned short* __restrict__ A,
                                                    const unsigned short* __restrict__ Bt,
                                                    const float* __restrict__ bias,
                                                    float* __restrict__ C,
                                                    int M, int N, int K) {
  __shared__ __align__(16) unsigned short sm[2][32768];
  const int tid = threadIdx.x;
  const int w = tid >> 6, lane = tid & 63;
  const int wm = w >> 2, wn = w & 3;

  // T1: XCD-aware swizzle (grid = 688, 688 % 8 == 0 -> exact)
  const int nbn = N / BN;
  const int cpx = gridDim.x >> 3;
  const int g = (blockIdx.x & 7) * cpx + (blockIdx.x >> 3);
  const int bm = g / nbn, bn = g % nbn;
  const int brow = bm * BM, bcol = bn * BN;

  // staging: thread covers row srow(+64, +h*128), pre-swizzled k chunk
  const int srow = tid >> 3;                                // 0..63
  const int kswz = ((tid & 7) ^ (srow & 7)) << 3;           // shorts
  const unsigned short* pA = A + (size_t)(brow + srow) * K + kswz;
  const unsigned short* pB = Bt + (size_t)(bcol + srow) * K + kswz;

  // frag reads: row R = base + (lane&15); col bytes = (ks*64+q*16) ^ ((R&7)<<4)
  const int aBase = (wm * 128 + (lane & 15)) * 64;          // shorts
  const int bBase = 16384 + (wn * 64 + (lane & 15)) * 64;
  const int col0 = (((lane >> 4) * 16) ^ ((lane & 7) << 4)) >> 1;        // shorts
  const int col1 = ((64 + (lane >> 4) * 16) ^ ((lane & 7) << 4)) >> 1;

  const int NKt = K / BK;

  f32x4 acc[8][4];
#pragma unroll
  for (int m = 0; m < 8; ++m)
#pragma unroll
    for (int n = 0; n < 4; ++n) acc[m][n] = (f32x4){0.f, 0.f, 0.f, 0.f};

  auto stage_half = [&](int s) {
    const int kt = s >> 2, h = s & 3;
    const unsigned short* src =
        ((h & 2) ? pB : pA) + (size_t)((h & 1) * 128) * K + (size_t)kt * BK;
    unsigned short* dst = &sm[kt & 1][(h << 13) + (w << 9)];
    gload16(src, dst);
    gload16(src + (size_t)64 * K, dst + 4096);
  };

  bf16x8 a0[4][2], a1[4][2], bb0[2][2], bb1[2][2];

  auto read_a0 = [&](const unsigned short* bp) {  // 8 ds_read_b128
#pragma unroll
    for (int m = 0; m < 4; ++m) {
      a0[m][0] = *(const bf16x8*)(bp + aBase + m * 1024 + col0);
      a0[m][1] = *(const bf16x8*)(bp + aBase + m * 1024 + col1);
    }
  };
  auto read_b0 = [&](const unsigned short* bp) {  // 4
#pragma unroll
    for (int n = 0; n < 2; ++n) {
      bb0[n][0] = *(const bf16x8*)(bp + bBase + n * 1024 + col0);
      bb0[n][1] = *(const bf16x8*)(bp + bBase + n * 1024 + col1);
    }
  };
  auto read_a1 = [&](const unsigned short* bp) {  // 8
#pragma unroll
    for (int m = 0; m < 4; ++m) {
      a1[m][0] = *(const bf16x8*)(bp + aBase + 4096 + m * 1024 + col0);
      a1[m][1] = *(const bf16x8*)(bp + aBase + 4096 + m * 1024 + col1);
    }
  };
  auto read_b1 = [&](const unsigned short* bp) {  // 4
#pragma unroll
    for (int n = 0; n < 2; ++n) {
      bb1[n][0] = *(const bf16x8*)(bp + bBase + (n + 2) * 1024 + col0);
      bb1[n][1] = *(const bf16x8*)(bp + bBase + (n + 2) * 1024 + col1);
    }
  };

  // prologue: stage tile 0, drain, barrier
  for (int h = 0; h < 4; ++h) stage_half(h);
  asm volatile("s_waitcnt vmcnt(0)" ::: "memory");
  __builtin_amdgcn_s_barrier();

  for (int t = 0; t < NKt; ++t) {
    const unsigned short* bp = sm[t & 1];

    // stage tile t+1 (writes buf[(t+1)&1]; safe per hazard analysis above)
    if (t + 1 < NKt) {
#pragma unroll
      for (int h = 0; h < 4; ++h) stage_half(4 * (t + 1) + h);
    }
    __builtin_amdgcn_sched_barrier(0);

    // issue all fragment reads, pinned group order: [a0,bb0][a1][bb1]
    read_a0(bp);
    read_b0(bp);
    __builtin_amdgcn_sched_barrier(0);
    read_a1(bp);
    __builtin_amdgcn_sched_barrier(0);
    read_b1(bp);
    __builtin_amdgcn_sched_barrier(0);

    // q0: needs a0+bb0 (first 12 reads)
    asm volatile("s_waitcnt lgkmcnt(12)" ::: "memory");
    __builtin_amdgcn_sched_barrier(0);
    __builtin_amdgcn_s_setprio(1);
#pragma unroll
    for (int kk = 0; kk < 2; ++kk)
#pragma unroll
      for (int m = 0; m < 4; ++m)
#pragma unroll
        for (int n = 0; n < 2; ++n)
          acc[m][n] = __builtin_amdgcn_mfma_f32_16x16x32_bf16(a0[m][kk], bb0[n][kk], acc[m][n], 0, 0, 0);
    __builtin_amdgcn_s_setprio(0);
    __builtin_amdgcn_sched_barrier(0);

    // q1: needs a1 (reads 13-20)
    asm volatile("s_waitcnt lgkmcnt(4)" ::: "memory");
    __builtin_amdgcn_sched_barrier(0);
    __builtin_amdgcn_s_setprio(1);
#pragma unroll
    for (int kk = 0; kk < 2; ++kk)
#pragma unroll
      for (int m = 0; m < 4; ++m)
#pragma unroll
        for (int n = 0; n < 2; ++n)
          acc[4 + m][n] = __builtin_amdgcn_mfma_f32_16x16x32_bf16(a1[m][kk], bb0[n][kk], acc[4 + m][n], 0, 0, 0);
    __builtin_amdgcn_s_setprio(0);
    __builtin_amdgcn_sched_barrier(0);

    // q2+q3: need bb1 (reads 21-24)
    asm volatile("s_waitcnt lgkmcnt(0)" ::: "memory");
    __builtin_amdgcn_sched_barrier(0);
    __builtin_amdgcn_s_setprio(1);
#pragma unroll
    for (int kk = 0; kk < 2; ++kk)
#pragma unroll
      for (int m = 0; m < 4; ++m)
#pragma unroll
        for (int n = 0; n < 2; ++n)
          acc[m][2 + n] = __builtin_amdgcn_mfma_f32_16x16x32_bf16(a0[m][kk], bb1[n][kk], acc[m][2 + n], 0, 0, 0);
#pragma unroll
    for (int kk = 0; kk < 2; ++kk)
#pragma unroll
      for (int m = 0; m < 4; ++m)
#pragma unroll
        for (int n = 0; n < 2; ++n)
          acc[4 + m][2 + n] = __builtin_amdgcn_mfma_f32_16x16x32_bf16(a1[m][kk], bb1[n][kk], acc[4 + m][2 + n], 0, 0, 0);
    __builtin_amdgcn_s_setprio(0);

    // tile boundary: staged data for t+1 landed; all waves' reads drained
    asm volatile("s_waitcnt vmcnt(0)" ::: "memory");
    __builtin_amdgcn_s_barrier();
  }

  // epilogue: C/D layout col=lane&15, row=(lane>>4)*4+reg
#pragma unroll
  for (int n = 0; n < 4; ++n) {
    const int col = bcol + wn * 64 + n * 16 + (lane & 15);
    const float bv = bias[col];
#pragma unroll
    for (int m = 0; m < 8; ++m) {
      const int row0 = brow + wm * 128 + m * 16 + ((lane >> 4) << 2);
#pragma unroll
      for (int q = 0; q < 4; ++q)
        C[(size_t)(row0 + q) * N + col] = acc[m][n][q] + bv;
    }
  }
}

// ---------------------------------------------------------------------------
extern "C" void kernel_launch(void* const* d_in, const int* in_sizes, int n_in,
                              void* d_out, int out_size, void* d_ws, size_t ws_size,
                              hipStream_t stream) {
  const float* x = (const float*)d_in[0];
  const int* qw = (const int*)d_in[1];
  const float* sc = (const float*)d_in[2];
  const int* qz = (const int*)d_in[3];
  const float* bias = (const float*)d_in[4];
  float* out = (float*)d_out;

  const int N = in_sizes[4];                              // 11008
  const int K = (int)(((long long)in_sizes[1] * 8) / N);  // 4096
  const int M = in_sizes[0] / K;                          // 4096

  const size_t a_elems = (size_t)M * K;
  const size_t b_elems = (size_t)N * K;
  const size_t need = (a_elems + b_elems) * sizeof(unsigned short);
  if (ws_size < need) return;

  unsigned short* A = (unsigned short*)d_ws;
  unsigned short* Bt = A + a_elems;

  convert_x<<<2048, 256, 0, stream>>>(x, A, (long long)(a_elems / 8));
  dequant_awq<<<(K / 64) * (N / 64), 256, 0, stream>>>(qw, sc, qz, Bt, K, N);
  gemm_bf16<<<(M / BM) * (N / BN), 512, 0, stream>>>(A, Bt, bias, out, M, N, K);
}

// Round 6
// 394.476 us; speedup vs baseline: 1.0733x; 1.0096x over previous
//
#include <hip/hip_runtime.h>

// ---------------------------------------------------------------------------
// AWQ int4 dequant GEMM: out = x @ dequant(qweight, scales, qzeros) + bias
// M=4096, K=4096, N=11008, group=128
//   1) convert_x: fp32->bf16 A[M][K]
//   2) dequant_awq: int4 -> bf16 Bt[N][K]
//   3) gemm_bf16: 256x256, BK=64, 512 thr, free-run tile body (1 barrier/tile,
//      counted lgkmcnt gates), XOR-swizzled LDS, bias fused.
//      NEW: 4bm x 8bn CLUSTER mapping per XCD -> per-XCD L2 reuse of A/B
//      k-slices, cutting L3 staging traffic ~5x.
// ---------------------------------------------------------------------------

typedef __bf16 bf16x8 __attribute__((ext_vector_type(8)));
typedef float f32x4 __attribute__((ext_vector_type(4)));
typedef unsigned short ushort8 __attribute__((ext_vector_type(8)));

__device__ __forceinline__ unsigned short f2bf(float f) {
  unsigned int u = __builtin_bit_cast(unsigned int, f);
  u += 0x7FFFu + ((u >> 16) & 1u);
  return (unsigned short)(u >> 16);
}

__device__ __forceinline__ void gload16(const void* g, void* l) {
  __builtin_amdgcn_global_load_lds(
      (const __attribute__((address_space(1))) unsigned int*)g,
      (__attribute__((address_space(3))) unsigned int*)l, 16, 0, 0);
}

// ---------------------------------------------------------------------------
// Kernel 1: x fp32 -> A bf16
// ---------------------------------------------------------------------------
__global__ __launch_bounds__(256) void convert_x(const float* __restrict__ x,
                                                 unsigned short* __restrict__ A,
                                                 long long n8) {
  for (long long idx = (long long)blockIdx.x * 256 + threadIdx.x; idx < n8;
       idx += (long long)gridDim.x * 256) {
    float4 u = ((const float4*)x)[2 * idx];
    float4 v = ((const float4*)x)[2 * idx + 1];
    ushort8 o;
    o[0] = f2bf(u.x); o[1] = f2bf(u.y); o[2] = f2bf(u.z); o[3] = f2bf(u.w);
    o[4] = f2bf(v.x); o[5] = f2bf(v.y); o[6] = f2bf(v.z); o[7] = f2bf(v.w);
    ((ushort8*)A)[idx] = o;
  }
}

// ---------------------------------------------------------------------------
// Kernel 2: AWQ dequant + transpose -> Bt bf16 [N][K]
// ---------------------------------------------------------------------------
__global__ __launch_bounds__(256) void dequant_awq(const int* __restrict__ qw,
                                                   const float* __restrict__ sc,
                                                   const int* __restrict__ qz,
                                                   unsigned short* __restrict__ Bt,
                                                   int K, int N) {
  const int n8w = N >> 3;
  const int tiles_n = N >> 6;
  const int tk = blockIdx.x / tiles_n;
  const int tn = blockIdx.x % tiles_n;
  const int k0 = tk << 6, n0 = tn << 6;
  const int g = k0 >> 7;
  __shared__ unsigned short tile[64][72];
  __shared__ float s_s[64];
  __shared__ float s_z[64];
  const int t = threadIdx.x;
  if (t < 64) {
    s_s[t] = sc[(size_t)g * N + n0 + t];
  } else if (t < 72) {
    const int j = t - 64;
    const int zq = qz[(size_t)g * n8w + (n0 >> 3) + j];
    s_z[j * 8 + 0] = (float)((zq >> 0) & 0xF);
    s_z[j * 8 + 1] = (float)((zq >> 16) & 0xF);
    s_z[j * 8 + 2] = (float)((zq >> 4) & 0xF);
    s_z[j * 8 + 3] = (float)((zq >> 20) & 0xF);
    s_z[j * 8 + 4] = (float)((zq >> 8) & 0xF);
    s_z[j * 8 + 5] = (float)((zq >> 24) & 0xF);
    s_z[j * 8 + 6] = (float)((zq >> 12) & 0xF);
    s_z[j * 8 + 7] = (float)((zq >> 28) & 0xF);
  }
  __syncthreads();
#pragma unroll
  for (int r = 0; r < 2; ++r) {
    const int d = (r << 8) + t;
    const int kk = d >> 3, j = d & 7;
    const int q = qw[(size_t)(k0 + kk) * n8w + (n0 >> 3) + j];
    const int base = j << 3;
    ushort8 o;
    o[0] = f2bf(((float)((q >> 0) & 0xF) - s_z[base + 0]) * s_s[base + 0]);
    o[1] = f2bf(((float)((q >> 16) & 0xF) - s_z[base + 1]) * s_s[base + 1]);
    o[2] = f2bf(((float)((q >> 4) & 0xF) - s_z[base + 2]) * s_s[base + 2]);
    o[3] = f2bf(((float)((q >> 20) & 0xF) - s_z[base + 3]) * s_s[base + 3]);
    o[4] = f2bf(((float)((q >> 8) & 0xF) - s_z[base + 4]) * s_s[base + 4]);
    o[5] = f2bf(((float)((q >> 24) & 0xF) - s_z[base + 5]) * s_s[base + 5]);
    o[6] = f2bf(((float)((q >> 12) & 0xF) - s_z[base + 6]) * s_s[base + 6]);
    o[7] = f2bf(((float)((q >> 28) & 0xF) - s_z[base + 7]) * s_s[base + 7]);
    *(ushort8*)&tile[kk][base] = o;
  }
  __syncthreads();
#pragma unroll
  for (int r = 0; r < 2; ++r) {
    const int d = (r << 8) + t;
    const int nl = d >> 3, seg = d & 7;
    ushort8 o;
#pragma unroll
    for (int i = 0; i < 8; ++i) o[i] = tile[(seg << 3) + i][nl];
    *(ushort8*)&Bt[(size_t)(n0 + nl) * K + k0 + (seg << 3)] = o;
  }
}

// ---------------------------------------------------------------------------
// Kernel 3: 256x256 free-run bf16 GEMM.  A [M][K], Bt [N][K], C fp32 [M][N].
// 8 waves (2M x 4N), per-wave 128x64 output = acc[8][4] f32x4.
// LDS: 2 bufs x (A[256][64] + B[256][64]) = 128 KiB, XOR-swizzled content.
// CLUSTER MAPPING: blockIdx%8 = XCD; slot = blockIdx/8; each group of 32
// slots on an XCD = one 4bm x 8bn cluster -> the XCD's 32 CUs co-run one
// cluster, so each A k-slice is L2-reused 8x and each B k-slice 4x.
// cluster ci = xcd + 8*(slot/32); bm = (ci&3)*4 + (t&3); bn = (ci>>2)*8 + t>>2.
// Per tile: ONE barrier; stage t+1 (8 gload16); 24 ds_read_b128 pinned
// [a0,bb0|a1|bb1]; lgkmcnt(12)->q0, (4)->q1, (0)->q2,q3; vmcnt(0); barrier.
// ---------------------------------------------------------------------------
#define BM 256
#define BN 256
#define BK 64

__global__ __launch_bounds__(512, 2) void gemm_bf16(const unsigned short* __restrict__ A,
                                                    const unsigned short* __restrict__ Bt,
                                                    const float* __restrict__ bias,
                                                    float* __restrict__ C,
                                                    int M, int N, int K) {
  __shared__ __align__(16) unsigned short sm[2][32768];
  const int tid = threadIdx.x;
  const int w = tid >> 6, lane = tid & 63;
  const int wm = w >> 2, wn = w & 3;

  // cluster mapping (L2 reuse within XCD)
  const int nbm = M / BM;                       // 16
  const int nbn = N / BN;                       // 43
  const int nclu = ((nbm + 3) >> 2) * ((nbn + 7) >> 3);
  const int xcd = blockIdx.x & 7;
  const int slot = blockIdx.x >> 3;
  const int ci = xcd + 8 * (slot >> 5);
  if (ci >= nclu) return;
  const int t32 = slot & 31;
  const int bm = (ci & 3) * 4 + (t32 & 3);
  const int bn = (ci >> 2) * 8 + (t32 >> 2);
  if (bm >= nbm || bn >= nbn) return;
  const int brow = bm * BM, bcol = bn * BN;

  // staging: thread covers row srow(+64, +h*128), pre-swizzled k chunk
  const int srow = tid >> 3;                                // 0..63
  const int kswz = ((tid & 7) ^ (srow & 7)) << 3;           // shorts
  const unsigned short* pA = A + (size_t)(brow + srow) * K + kswz;
  const unsigned short* pB = Bt + (size_t)(bcol + srow) * K + kswz;

  // frag reads: row R = base + (lane&15); col bytes = (ks*64+q*16) ^ ((R&7)<<4)
  const int aBase = (wm * 128 + (lane & 15)) * 64;          // shorts
  const int bBase = 16384 + (wn * 64 + (lane & 15)) * 64;
  const int col0 = (((lane >> 4) * 16) ^ ((lane & 7) << 4)) >> 1;        // shorts
  const int col1 = ((64 + (lane >> 4) * 16) ^ ((lane & 7) << 4)) >> 1;

  const int NKt = K / BK;

  f32x4 acc[8][4];
#pragma unroll
  for (int m = 0; m < 8; ++m)
#pragma unroll
    for (int n = 0; n < 4; ++n) acc[m][n] = (f32x4){0.f, 0.f, 0.f, 0.f};

  auto stage_half = [&](int s) {
    const int kt = s >> 2, h = s & 3;
    const unsigned short* src =
        ((h & 2) ? pB : pA) + (size_t)((h & 1) * 128) * K + (size_t)kt * BK;
    unsigned short* dst = &sm[kt & 1][(h << 13) + (w << 9)];
    gload16(src, dst);
    gload16(src + (size_t)64 * K, dst + 4096);
  };

  bf16x8 a0[4][2], a1[4][2], bb0[2][2], bb1[2][2];

  auto read_a0 = [&](const unsigned short* bp) {  // 8 ds_read_b128
#pragma unroll
    for (int m = 0; m < 4; ++m) {
      a0[m][0] = *(const bf16x8*)(bp + aBase + m * 1024 + col0);
      a0[m][1] = *(const bf16x8*)(bp + aBase + m * 1024 + col1);
    }
  };
  auto read_b0 = [&](const unsigned short* bp) {  // 4
#pragma unroll
    for (int n = 0; n < 2; ++n) {
      bb0[n][0] = *(const bf16x8*)(bp + bBase + n * 1024 + col0);
      bb0[n][1] = *(const bf16x8*)(bp + bBase + n * 1024 + col1);
    }
  };
  auto read_a1 = [&](const unsigned short* bp) {  // 8
#pragma unroll
    for (int m = 0; m < 4; ++m) {
      a1[m][0] = *(const bf16x8*)(bp + aBase + 4096 + m * 1024 + col0);
      a1[m][1] = *(const bf16x8*)(bp + aBase + 4096 + m * 1024 + col1);
    }
  };
  auto read_b1 = [&](const unsigned short* bp) {  // 4
#pragma unroll
    for (int n = 0; n < 2; ++n) {
      bb1[n][0] = *(const bf16x8*)(bp + bBase + (n + 2) * 1024 + col0);
      bb1[n][1] = *(const bf16x8*)(bp + bBase + (n + 2) * 1024 + col1);
    }
  };

  // prologue: stage tile 0, drain, barrier
  for (int h = 0; h < 4; ++h) stage_half(h);
  asm volatile("s_waitcnt vmcnt(0)" ::: "memory");
  __builtin_amdgcn_s_barrier();

  for (int t = 0; t < NKt; ++t) {
    const unsigned short* bp = sm[t & 1];

    // stage tile t+1 (writes buf[(t+1)&1]; safe: that buf last read in t-1,
    // drained by lgkmcnt(0) before the tile-t barrier)
    if (t + 1 < NKt) {
#pragma unroll
      for (int h = 0; h < 4; ++h) stage_half(4 * (t + 1) + h);
    }
    __builtin_amdgcn_sched_barrier(0);

    // issue all fragment reads, pinned group order: [a0,bb0][a1][bb1]
    read_a0(bp);
    read_b0(bp);
    __builtin_amdgcn_sched_barrier(0);
    read_a1(bp);
    __builtin_amdgcn_sched_barrier(0);
    read_b1(bp);
    __builtin_amdgcn_sched_barrier(0);

    // q0: needs a0+bb0 (first 12 reads)
    asm volatile("s_waitcnt lgkmcnt(12)" ::: "memory");
    __builtin_amdgcn_sched_barrier(0);
    __builtin_amdgcn_s_setprio(1);
#pragma unroll
    for (int kk = 0; kk < 2; ++kk)
#pragma unroll
      for (int m = 0; m < 4; ++m)
#pragma unroll
        for (int n = 0; n < 2; ++n)
          acc[m][n] = __builtin_amdgcn_mfma_f32_16x16x32_bf16(a0[m][kk], bb0[n][kk], acc[m][n], 0, 0, 0);
    __builtin_amdgcn_s_setprio(0);
    __builtin_amdgcn_sched_barrier(0);

    // q1: needs a1 (reads 13-20)
    asm volatile("s_waitcnt lgkmcnt(4)" ::: "memory");
    __builtin_amdgcn_sched_barrier(0);
    __builtin_amdgcn_s_setprio(1);
#pragma unroll
    for (int kk = 0; kk < 2; ++kk)
#pragma unroll
      for (int m = 0; m < 4; ++m)
#pragma unroll
        for (int n = 0; n < 2; ++n)
          acc[4 + m][n] = __builtin_amdgcn_mfma_f32_16x16x32_bf16(a1[m][kk], bb0[n][kk], acc[4 + m][n], 0, 0, 0);
    __builtin_amdgcn_s_setprio(0);
    __builtin_amdgcn_sched_barrier(0);

    // q2+q3: need bb1 (reads 21-24)
    asm volatile("s_waitcnt lgkmcnt(0)" ::: "memory");
    __builtin_amdgcn_sched_barrier(0);
    __builtin_amdgcn_s_setprio(1);
#pragma unroll
    for (int kk = 0; kk < 2; ++kk)
#pragma unroll
      for (int m = 0; m < 4; ++m)
#pragma unroll
        for (int n = 0; n < 2; ++n)
          acc[m][2 + n] = __builtin_amdgcn_mfma_f32_16x16x32_bf16(a0[m][kk], bb1[n][kk], acc[m][2 + n], 0, 0, 0);
#pragma unroll
    for (int kk = 0; kk < 2; ++kk)
#pragma unroll
      for (int m = 0; m < 4; ++m)
#pragma unroll
        for (int n = 0; n < 2; ++n)
          acc[4 + m][2 + n] = __builtin_amdgcn_mfma_f32_16x16x32_bf16(a1[m][kk], bb1[n][kk], acc[4 + m][2 + n], 0, 0, 0);
    __builtin_amdgcn_s_setprio(0);

    // tile boundary: staged data for t+1 landed; all waves' reads drained
    asm volatile("s_waitcnt vmcnt(0)" ::: "memory");
    __builtin_amdgcn_s_barrier();
  }

  // epilogue: C/D layout col=lane&15, row=(lane>>4)*4+reg
#pragma unroll
  for (int n = 0; n < 4; ++n) {
    const int col = bcol + wn * 64 + n * 16 + (lane & 15);
    const float bv = bias[col];
#pragma unroll
    for (int m = 0; m < 8; ++m) {
      const int row0 = brow + wm * 128 + m * 16 + ((lane >> 4) << 2);
#pragma unroll
      for (int q = 0; q < 4; ++q)
        C[(size_t)(row0 + q) * N + col] = acc[m][n][q] + bv;
    }
  }
}

// ---------------------------------------------------------------------------
extern "C" void kernel_launch(void* const* d_in, const int* in_sizes, int n_in,
                              void* d_out, int out_size, void* d_ws, size_t ws_size,
                              hipStream_t stream) {
  const float* x = (const float*)d_in[0];
  const int* qw = (const int*)d_in[1];
  const float* sc = (const float*)d_in[2];
  const int* qz = (const int*)d_in[3];
  const float* bias = (const float*)d_in[4];
  float* out = (float*)d_out;

  const int N = in_sizes[4];                              // 11008
  const int K = (int)(((long long)in_sizes[1] * 8) / N);  // 4096
  const int M = in_sizes[0] / K;                          // 4096

  const size_t a_elems = (size_t)M * K;
  const size_t b_elems = (size_t)N * K;
  const size_t need = (a_elems + b_elems) * sizeof(unsigned short);
  if (ws_size < need) return;

  unsigned short* A = (unsigned short*)d_ws;
  unsigned short* Bt = A + a_elems;

  convert_x<<<2048, 256, 0, stream>>>(x, A, (long long)(a_elems / 8));
  dequant_awq<<<(K / 64) * (N / 64), 256, 0, stream>>>(qw, sc, qz, Bt, K, N);

  const int nbm = M / BM, nbn = N / BN;
  const int nclu = ((nbm + 3) / 4) * ((nbn + 7) / 8);
  const int grid = 8 * 32 * ((nclu + 7) / 8);
  gemm_bf16<<<grid, 512, 0, stream>>>(A, Bt, bias, out, M, N, K);
}